// Round 1
// baseline (55.440 us; speedup 1.0000x reference)
//
#include <hip/hip_runtime.h>
#include <math.h>

// Problem constants
#define N_  32
#define C_  256
#define K_  6
#define M_  22
#define HO_ 17

static constexpr int OUT0_SZ = N_ * HO_ * HO_;        // 9248
static constexpr int XF_OFF  = OUT0_SZ;               // xf starts here
static constexpr int XF_SZ   = N_ * C_ * M_ * M_;     // 3964928
static constexpr int ZF_OFF  = XF_OFF + XF_SZ;        // 3974176
// total out = ZF_OFF + N_*C_*K_*K_ = 4269088

// ---------------------------------------------------------------------------
// Kernel 1: siamese branch (1x1 conv over 3 ch -> 256 ch, + bias, ReLU)
// for both x (N,3,22,22)->xf (N,256,22,22) and z (N,3,6,6)->zf (N,256,6,6).
// One block per (n, o). 484 = 121 float4; 36 = 9 float4.
// ---------------------------------------------------------------------------
__global__ __launch_bounds__(128) void k_branch(
    const float* __restrict__ z, const float* __restrict__ x,
    const float* __restrict__ Wb, const float* __restrict__ bb,
    float* __restrict__ out)
{
    const int blk = blockIdx.x;
    const int n = blk >> 8;       // blk / 256
    const int o = blk & 255;
    const float w0 = Wb[o * 3 + 0];
    const float w1 = Wb[o * 3 + 1];
    const float w2 = Wb[o * 3 + 2];
    const float bias = bb[o];
    const int t = threadIdx.x;

    if (t < 121) {
        const float4* xb = (const float4*)(x + (size_t)n * 3 * 484);
        float4 a = xb[t];
        float4 b = xb[121 + t];
        float4 c = xb[242 + t];
        float4 r;
        r.x = fmaxf(0.f, fmaf(a.x, w0, fmaf(b.x, w1, fmaf(c.x, w2, bias))));
        r.y = fmaxf(0.f, fmaf(a.y, w0, fmaf(b.y, w1, fmaf(c.y, w2, bias))));
        r.z = fmaxf(0.f, fmaf(a.z, w0, fmaf(b.z, w1, fmaf(c.z, w2, bias))));
        r.w = fmaxf(0.f, fmaf(a.w, w0, fmaf(b.w, w1, fmaf(c.w, w2, bias))));
        ((float4*)(out + XF_OFF + (size_t)(n * C_ + o) * 484))[t] = r;
    }
    if (t >= 119) {               // t in [119,128): 9 threads cover zf (9 float4)
        const int t2 = t - 119;
        const float4* zb = (const float4*)(z + (size_t)n * 3 * 36);
        float4 a = zb[t2];
        float4 b = zb[9 + t2];
        float4 c = zb[18 + t2];
        float4 r;
        r.x = fmaxf(0.f, fmaf(a.x, w0, fmaf(b.x, w1, fmaf(c.x, w2, bias))));
        r.y = fmaxf(0.f, fmaf(a.y, w0, fmaf(b.y, w1, fmaf(c.y, w2, bias))));
        r.z = fmaxf(0.f, fmaf(a.z, w0, fmaf(b.z, w1, fmaf(c.z, w2, bias))));
        r.w = fmaxf(0.f, fmaf(a.w, w0, fmaf(b.w, w1, fmaf(c.w, w2, bias))));
        ((float4*)(out + ZF_OFF + (size_t)(n * C_ + o) * 36))[t2] = r;
    }
}

// ---------------------------------------------------------------------------
// Kernel 2: Bhattacharyya correlation.
// out_pre[n,i,j] = (1/36) * sum_{c,kh,kw} w[c]*sqrt(zf[n,c,kh,kw])*sqrt(xf[n,c,i+kh,j+kw])
// One block per (n, i) output row; 256 threads = one channel each.
// Each thread register-blocks the full 17-wide output row with a 22-float
// sliding window; then butterfly + LDS reduce over channels.
// ---------------------------------------------------------------------------
__global__ __launch_bounds__(256) void k_bhat(
    const float* __restrict__ wv, float* __restrict__ out)
{
    const int blk = blockIdx.x;
    const int n = blk / HO_;
    const int i = blk % HO_;
    const int c = threadIdx.x;    // channel

    float acc[HO_];
#pragma unroll
    for (int j = 0; j < HO_; ++j) acc[j] = 0.f;

    // z-side: w[c] * sqrt(zf), kept in registers (static indexing only)
    const float wc = wv[c];
    const float* zfp = out + ZF_OFF + (size_t)(n * C_ + c) * 36;
    float szv[36];
#pragma unroll
    for (int kk = 0; kk < 36; ++kk) szv[kk] = wc * sqrtf(zfp[kk]);

    const float* xfp = out + XF_OFF + (size_t)(n * C_ + c) * 484;
#pragma unroll
    for (int kh = 0; kh < K_; ++kh) {
        const float* row = xfp + (i + kh) * 22;
        float r[22];
#pragma unroll
        for (int u = 0; u < 22; ++u) r[u] = sqrtf(row[u]);
#pragma unroll
        for (int kw = 0; kw < K_; ++kw) {
            const float s = szv[kh * 6 + kw];
#pragma unroll
            for (int j = 0; j < HO_; ++j)
                acc[j] = fmaf(s, r[j + kw], acc[j]);
        }
    }

    // reduce over 64 lanes (wave = 64 channels)
#pragma unroll
    for (int off = 1; off < 64; off <<= 1) {
#pragma unroll
        for (int j = 0; j < HO_; ++j)
            acc[j] += __shfl_xor(acc[j], off, 64);
    }

    __shared__ float red[4][HO_];
    const int wave = threadIdx.x >> 6;
    const int lane = threadIdx.x & 63;
    if (lane == 0) {
#pragma unroll
        for (int j = 0; j < HO_; ++j) red[wave][j] = acc[j];
    }
    __syncthreads();
    if (threadIdx.x < HO_) {
        const int j = threadIdx.x;
        float v = red[0][j] + red[1][j] + red[2][j] + red[3][j];
        out[n * (HO_ * HO_) + i * HO_ + j] = v * (1.f / 36.f);
    }
}

// ---------------------------------------------------------------------------
// Kernel 3: training-mode BatchNorm over all 9248 values, in place.
// Single block => deterministic. Two-pass (mean, then centered var).
// ---------------------------------------------------------------------------
__global__ __launch_bounds__(1024) void k_bn(
    const float* __restrict__ gamma, const float* __restrict__ beta,
    float* __restrict__ out)
{
    constexpr int TOT = OUT0_SZ;          // 9248
    constexpr int PER = 10;               // 10*1024 >= 9248
    const int t = threadIdx.x;

    __shared__ float lds[17];

    float v[PER];
    float sum = 0.f;
#pragma unroll
    for (int k = 0; k < PER; ++k) {
        const int idx = t + k * 1024;
        v[k] = (idx < TOT) ? out[idx] : 0.f;
        sum += v[k];
    }

    // block reduce: sum
#pragma unroll
    for (int off = 1; off < 64; off <<= 1) sum += __shfl_xor(sum, off, 64);
    const int wave = t >> 6, lane = t & 63;
    if (lane == 0) lds[wave] = sum;
    __syncthreads();
    if (t == 0) {
        float s = 0.f;
#pragma unroll
        for (int w = 0; w < 16; ++w) s += lds[w];
        lds[16] = s;
    }
    __syncthreads();
    const float mu = lds[16] / (float)TOT;
    __syncthreads();   // safe LDS reuse

    // block reduce: centered sum of squares
    float sq = 0.f;
#pragma unroll
    for (int k = 0; k < PER; ++k) {
        const int idx = t + k * 1024;
        if (idx < TOT) {
            const float d = v[k] - mu;
            sq += d * d;
        }
    }
#pragma unroll
    for (int off = 1; off < 64; off <<= 1) sq += __shfl_xor(sq, off, 64);
    if (lane == 0) lds[wave] = sq;
    __syncthreads();
    if (t == 0) {
        float s = 0.f;
#pragma unroll
        for (int w = 0; w < 16; ++w) s += lds[w];
        lds[16] = s;
    }
    __syncthreads();
    const float var = lds[16] / (float)TOT;

    const float scale = gamma[0] / sqrtf(var + 1e-5f);
    const float shift = beta[0];
#pragma unroll
    for (int k = 0; k < PER; ++k) {
        const int idx = t + k * 1024;
        if (idx < TOT) out[idx] = (v[k] - mu) * scale + shift;
    }
}

// ---------------------------------------------------------------------------
extern "C" void kernel_launch(void* const* d_in, const int* in_sizes, int n_in,
                              void* d_out, int out_size, void* d_ws, size_t ws_size,
                              hipStream_t stream) {
    const float* z     = (const float*)d_in[0];
    const float* x     = (const float*)d_in[1];
    const float* Wb    = (const float*)d_in[2];
    const float* bb    = (const float*)d_in[3];
    const float* wv    = (const float*)d_in[4];
    const float* gamma = (const float*)d_in[5];
    const float* beta  = (const float*)d_in[6];
    float* out = (float*)d_out;

    k_branch<<<N_ * C_, 128, 0, stream>>>(z, x, Wb, bb, out);
    k_bhat<<<N_ * HO_, 256, 0, stream>>>(wv, out);
    k_bn<<<1, 1024, 0, stream>>>(gamma, beta, out);
}

// Round 2
// 41.132 us; speedup vs baseline: 1.3479x; 1.3479x over previous
//
#include <hip/hip_runtime.h>
#include <math.h>

// Problem constants
#define N_  32
#define C_  256
#define K_  6
#define M_  22
#define HO_ 17
#define P_  484            // 22*22
#define ZP_ 36             // 6*6

static constexpr int OUT0_SZ = N_ * HO_ * HO_;        // 9248
static constexpr int XF_OFF  = OUT0_SZ;               // xf starts here
static constexpr int XF_SZ   = N_ * C_ * P_;          // 3964928
static constexpr int ZF_OFF  = XF_OFF + XF_SZ;        // 3974176
// ws layout (floats): sxT (N,484,256) then szT (N,36,256)
static constexpr size_t SXT_SZ = (size_t)N_ * P_ * C_;   // 3964928
// total ws use ~20 MB << 256 MB

// ---------------------------------------------------------------------------
// Kernel 1: siamese branch for x and z, producing:
//   - xf (N,C,484), zf (N,C,36) into d_out (required outputs), coalesced
//   - sxT (N,484,C) = sqrt(xf)      into ws  (channels-last, via LDS transpose)
//   - szT (N,36,C)  = w[c]/36*sqrt(zf) into ws (channels-last)
// Block = (n, og) with og = 32-channel group; 256 threads.
// ---------------------------------------------------------------------------
__global__ __launch_bounds__(256) void k_branch2(
    const float* __restrict__ z, const float* __restrict__ x,
    const float* __restrict__ Wb, const float* __restrict__ bb,
    const float* __restrict__ wv,
    float* __restrict__ out, float* __restrict__ ws)
{
    const int n  = blockIdx.x >> 3;
    const int og = blockIdx.x & 7;        // 32 channels per group
    const int t  = threadIdx.x;

    __shared__ float xs[3 * P_];          // staged x[n]
    __shared__ float zs[3 * ZP_];         // staged z[n]
    __shared__ float lw[32][4];           // per-channel w0,w1,w2,bias
    __shared__ float tile[64][33];        // p-major transpose tile (pad 33)

    // ---- stage inputs ----
    const float* xp = x + (size_t)n * (3 * P_);
    for (int idx = t; idx < 3 * P_; idx += 256) xs[idx] = xp[idx];
    const float* zp = z + (size_t)n * (3 * ZP_);
    if (t < 3 * ZP_) zs[t] = zp[t];
    if (t < 32) {
        const int c = og * 32 + t;
        lw[t][0] = Wb[c * 3 + 0];
        lw[t][1] = Wb[c * 3 + 1];
        lw[t][2] = Wb[c * 3 + 2];
        lw[t][3] = bb[c];
    }
    __syncthreads();

    float* sxT = ws;
    float* szT = ws + SXT_SZ;

    // ---- z branch + szT (tiny: 32 ch * 36 = 1152 values) ----
    for (int idx = t; idx < 32 * ZP_; idx += 256) {
        const int cl = idx / ZP_;
        const int k  = idx % ZP_;
        const int c  = og * 32 + cl;
        const float v = fmaxf(0.f,
            fmaf(zs[k], lw[cl][0],
            fmaf(zs[ZP_ + k], lw[cl][1],
            fmaf(zs[2 * ZP_ + k], lw[cl][2], lw[cl][3]))));
        out[ZF_OFF + (size_t)(n * C_ + c) * ZP_ + k] = v;
        szT[(size_t)n * ZP_ * C_ + (size_t)k * C_ + c] = wv[c] * (1.f / 36.f) * sqrtf(v);
    }

    // ---- x branch: 8 p-tiles of 64; compute lanes-along-p, transpose in LDS ----
    const int p_lane = t & 63;
    const int cq     = t >> 6;            // 0..3
    const int c2     = t & 31;
    const int pr     = t >> 5;            // 0..7

    for (int pt = 0; pt < 8; ++pt) {
        const int p = pt * 64 + p_lane;
        if (p < P_) {
            const float a = xs[p];
            const float b = xs[P_ + p];
            const float d = xs[2 * P_ + p];
#pragma unroll
            for (int r = 0; r < 8; ++r) {
                const int cl = cq + r * 4;        // 0..31
                const int c  = og * 32 + cl;
                const float v = fmaxf(0.f,
                    fmaf(a, lw[cl][0], fmaf(b, lw[cl][1], fmaf(d, lw[cl][2], lw[cl][3]))));
                out[XF_OFF + (size_t)(n * C_ + c) * P_ + p] = v;   // coalesced along p
                tile[p_lane][cl] = sqrtf(v);
            }
        }
        __syncthreads();
#pragma unroll
        for (int r = 0; r < 8; ++r) {
            const int p2 = pt * 64 + pr + r * 8;
            if (p2 < P_)
                sxT[(size_t)n * P_ * C_ + (size_t)p2 * C_ + og * 32 + c2] = tile[pr + r * 8][c2];
        }
        __syncthreads();
    }
}

// ---------------------------------------------------------------------------
// Kernel 2: Bhattacharyya from channels-last pre-sqrt'd tensors.
// out_pre[n,i,j] = sum_{c,kh,kw} szT[n,kh*6+kw,c] * sxT[n,(i+kh)*22+(j+kw),c]
// Block = (n, i); 256 threads = channel. All loads coalesced (lane = c).
// Register sliding window: 612 FMA/thread, acc[17]; butterfly+LDS reduce.
// ---------------------------------------------------------------------------
__global__ __launch_bounds__(256) void k_bhat2(
    const float* __restrict__ ws, float* __restrict__ out)
{
    const int blk = blockIdx.x;
    const int n = blk / HO_;
    const int i = blk % HO_;
    const int c = threadIdx.x;

    const float* sxT = ws;
    const float* szT = ws + SXT_SZ;

    float szv[ZP_];
    const float* szp = szT + (size_t)n * ZP_ * C_ + c;
#pragma unroll
    for (int k = 0; k < ZP_; ++k) szv[k] = szp[(size_t)k * C_];

    float acc[HO_];
#pragma unroll
    for (int j = 0; j < HO_; ++j) acc[j] = 0.f;

    const float* sxp = sxT + (size_t)n * P_ * C_ + c;
#pragma unroll
    for (int kh = 0; kh < K_; ++kh) {
        const float* rp = sxp + (size_t)(i + kh) * 22 * C_;
        float r[22];
#pragma unroll
        for (int u = 0; u < 22; ++u) r[u] = rp[(size_t)u * C_];
#pragma unroll
        for (int kw = 0; kw < K_; ++kw) {
            const float s = szv[kh * 6 + kw];
#pragma unroll
            for (int j = 0; j < HO_; ++j)
                acc[j] = fmaf(s, r[j + kw], acc[j]);
        }
    }

    // reduce across 64 lanes, then across the 4 waves
#pragma unroll
    for (int off = 1; off < 64; off <<= 1) {
#pragma unroll
        for (int j = 0; j < HO_; ++j)
            acc[j] += __shfl_xor(acc[j], off, 64);
    }

    __shared__ float red[4][HO_];
    const int wave = threadIdx.x >> 6;
    const int lane = threadIdx.x & 63;
    if (lane == 0) {
#pragma unroll
        for (int j = 0; j < HO_; ++j) red[wave][j] = acc[j];
    }
    __syncthreads();
    if (threadIdx.x < HO_) {
        const int j = threadIdx.x;
        out[n * (HO_ * HO_) + i * HO_ + j] =
            red[0][j] + red[1][j] + red[2][j] + red[3][j];
    }
}

// ---------------------------------------------------------------------------
// Kernel 3: training-mode BatchNorm over all 9248 values, in place.
// Single block => deterministic. Two-pass centered (cancellation-safe).
// ---------------------------------------------------------------------------
__global__ __launch_bounds__(1024) void k_bn(
    const float* __restrict__ gamma, const float* __restrict__ beta,
    float* __restrict__ out)
{
    constexpr int TOT = OUT0_SZ;          // 9248
    constexpr int PER = 10;               // 10*1024 >= 9248
    const int t = threadIdx.x;

    __shared__ float lds[17];

    float v[PER];
    float sum = 0.f;
#pragma unroll
    for (int k = 0; k < PER; ++k) {
        const int idx = t + k * 1024;
        v[k] = (idx < TOT) ? out[idx] : 0.f;
        sum += v[k];
    }

#pragma unroll
    for (int off = 1; off < 64; off <<= 1) sum += __shfl_xor(sum, off, 64);
    const int wave = t >> 6, lane = t & 63;
    if (lane == 0) lds[wave] = sum;
    __syncthreads();
    if (t == 0) {
        float s = 0.f;
#pragma unroll
        for (int w = 0; w < 16; ++w) s += lds[w];
        lds[16] = s;
    }
    __syncthreads();
    const float mu = lds[16] / (float)TOT;
    __syncthreads();

    float sq = 0.f;
#pragma unroll
    for (int k = 0; k < PER; ++k) {
        const int idx = t + k * 1024;
        if (idx < TOT) {
            const float d = v[k] - mu;
            sq += d * d;
        }
    }
#pragma unroll
    for (int off = 1; off < 64; off <<= 1) sq += __shfl_xor(sq, off, 64);
    if (lane == 0) lds[wave] = sq;
    __syncthreads();
    if (t == 0) {
        float s = 0.f;
#pragma unroll
        for (int w = 0; w < 16; ++w) s += lds[w];
        lds[16] = s;
    }
    __syncthreads();
    const float var = lds[16] / (float)TOT;

    const float scale = gamma[0] / sqrtf(var + 1e-5f);
    const float shift = beta[0];
#pragma unroll
    for (int k = 0; k < PER; ++k) {
        const int idx = t + k * 1024;
        if (idx < TOT) out[idx] = (v[k] - mu) * scale + shift;
    }
}

// ---------------------------------------------------------------------------
extern "C" void kernel_launch(void* const* d_in, const int* in_sizes, int n_in,
                              void* d_out, int out_size, void* d_ws, size_t ws_size,
                              hipStream_t stream) {
    const float* z     = (const float*)d_in[0];
    const float* x     = (const float*)d_in[1];
    const float* Wb    = (const float*)d_in[2];
    const float* bb    = (const float*)d_in[3];
    const float* wv    = (const float*)d_in[4];
    const float* gamma = (const float*)d_in[5];
    const float* beta  = (const float*)d_in[6];
    float* out = (float*)d_out;
    float* ws  = (float*)d_ws;

    k_branch2<<<N_ * 8, 256, 0, stream>>>(z, x, Wb, bb, wv, out, ws);
    k_bhat2<<<N_ * HO_, 256, 0, stream>>>(ws, out);
    k_bn<<<1, 1024, 0, stream>>>(gamma, beta, out);
}